// Round 1
// baseline (591.719 us; speedup 1.0000x reference)
//
#include <hip/hip_runtime.h>
#include <math.h>
#include <stdint.h>

#define BB 4
#define NN 4096
#define DD 1024
#define TT (BB * NN)          // 16384 tokens
#define NC 64                 // scan chunks
#define CL (NN / NC)          // 64 steps per chunk

typedef __attribute__((ext_vector_type(8))) short bf16x8;
typedef __attribute__((ext_vector_type(4))) float f32x4;

// bf16 round-to-nearest-even (returns top-16 bit pattern)
__device__ inline unsigned short bf_rne(float v) {
  union { float f; uint32_t u; } x; x.f = v;
  uint32_t r = x.u + 0x7fffu + ((x.u >> 16) & 1u);
  return (unsigned short)(r >> 16);
}
__device__ inline float bf_to_f(unsigned short h) {
  union { float f; uint32_t u; } x; x.u = ((uint32_t)h) << 16;
  return x.f;
}

// async global->LDS, 16 bytes per lane, deposits at (wave-uniform base + lane*16)
__device__ inline void async16(const void* g, void* l) {
  __builtin_amdgcn_global_load_lds(
      (const __attribute__((address_space(1))) uint32_t*)g,
      (__attribute__((address_space(3))) uint32_t*)l, 16, 0, 0);
}

// ---------------------------------------------------------------------------
// conv_x: x (b,n,d) fp32 -> Abf (t = n*4+b, 1024) bf16
// ---------------------------------------------------------------------------
__global__ __launch_bounds__(256) void conv_x_kernel(
    const float* __restrict__ x, unsigned short* __restrict__ Abf) {
  int idx = blockIdx.x * 256 + threadIdx.x;     // over BB*NN*DD
  int k = idx & 1023;
  int n = (idx >> 10) & 4095;
  int b = idx >> 22;
  Abf[(size_t)(n * 4 + b) * 1024 + k] = bf_rne(x[idx]);
}

// ---------------------------------------------------------------------------
// conv_w1: rows [in_w(2048); nu_w(1024)] (e,1024) fp32 -> W1 bf16
// ---------------------------------------------------------------------------
__global__ __launch_bounds__(256) void conv_w1_kernel(
    const float* __restrict__ in_w, const float* __restrict__ nu_w,
    unsigned short* __restrict__ W1) {
  int idx = blockIdx.x * 256 + threadIdx.x;     // over 3072*1024
  float v = (idx < 2048 * 1024) ? in_w[idx] : nu_w[idx - 2048 * 1024];
  W1[idx] = bf_rne(v);
}

// ---------------------------------------------------------------------------
// conv_w2: out_w (j, 2048) fp32 -> W2 (j, 2048) bf16, (r,i)-interleaved:
// W2[j][2d] = out_w[j][d], W2[j][2d+1] = out_w[j][1024+d]
// ---------------------------------------------------------------------------
__global__ __launch_bounds__(256) void conv_w2_kernel(
    const float* __restrict__ out_w, unsigned short* __restrict__ W2) {
  int idx = blockIdx.x * 256 + threadIdx.x;     // over 1024*1024
  int j = idx >> 10, d = idx & 1023;
  W2[(size_t)j * 2048 + 2 * d]     = bf_rne(out_w[(size_t)j * 2048 + d]);
  W2[(size_t)j * 2048 + 2 * d + 1] = bf_rne(out_w[(size_t)j * 2048 + 1024 + d]);
}

// ---------------------------------------------------------------------------
// GEMM1 (MFMA): z = Abf[t,:] . W1[e,:], K=1024 bf16. 128x128 tile, BK=64,
// 4 waves, each 4x4 of 16x16x32 MFMA.
// Round-5 change: LDS DOUBLE-BUFFER (T3-minimum 2-phase): issue next K-step's
// global_load_lds BEFORE computing current one; single __syncthreads per
// K-step (its vmcnt(0)+lgkmcnt(0) drain covers both the staged loads for
// buf^1 and the ds_reads of buf before the next overwrite). HBM latency now
// hides under the MFMA block intra-block, so 2 blocks/CU suffice
// (__launch_bounds__(256,2); 64 KB LDS caps us there anyway).
// Epilogue:
//   e < 2048 : U16[t,e]  = bf16( gamma[e>>1]*(z + in_b[e]) )   (u interleaved)
//   e >= 2048: NU[t,e']  = fp16( sigmoid(z + nu_b[e']) )
// ---------------------------------------------------------------------------
__global__ __launch_bounds__(256, 2) void gemm1_mfma(
    const unsigned short* __restrict__ A,
    const unsigned short* __restrict__ W1,
    const float* __restrict__ in_b, const float* __restrict__ nu_b,
    const float* __restrict__ gamma_log,
    unsigned short* __restrict__ U16, _Float16* __restrict__ NU) {
  __shared__ unsigned short As[2][8192];   // 2 x 16 KB
  __shared__ unsigned short Bs[2][8192];   // 2 x 16 KB
  const int tid = threadIdx.x;
  const int w = tid >> 6, l = tid & 63;
  const int q = l >> 4, ml = l & 15;
  const int m0 = blockIdx.y * 128;
  const int n0 = blockIdx.x * 128;
  const int wm = w & 1, wn = w >> 1;

  f32x4 acc[4][4] = {};

  auto stage = [&](int p, int k0) {
#pragma unroll
    for (int h = 0; h < 2; ++h) {
      int kq = 2 * w + h;     // wave w stages kq slices 2w, 2w+1
      async16(A + (size_t)(m0 + l) * 1024 + k0 + kq * 8, &As[p][(kq * 128) * 8]);
      async16(A + (size_t)(m0 + 64 + l) * 1024 + k0 + kq * 8, &As[p][(kq * 128 + 64) * 8]);
      async16(W1 + (size_t)(n0 + l) * 1024 + k0 + kq * 8, &Bs[p][(kq * 128) * 8]);
      async16(W1 + (size_t)(n0 + 64 + l) * 1024 + k0 + kq * 8, &Bs[p][(kq * 128 + 64) * 8]);
    }
  };

  stage(0, 0);
  __syncthreads();            // drains vmcnt(0): buf0 ready
  int cur = 0;
  for (int k0 = 0; k0 < 1024; k0 += 64) {
    if (k0 + 64 < 1024) stage(cur ^ 1, k0 + 64);   // prefetch next K-step
#pragma unroll
    for (int s = 0; s < 2; ++s) {
      bf16x8 af[4], bfr[4];
#pragma unroll
      for (int i = 0; i < 4; ++i)
        af[i] = *(const bf16x8*)&As[cur][(((s * 4 + q) * 128) + wm * 64 + i * 16 + ml) * 8];
#pragma unroll
      for (int j = 0; j < 4; ++j)
        bfr[j] = *(const bf16x8*)&Bs[cur][(((s * 4 + q) * 128) + wn * 64 + j * 16 + ml) * 8];
#pragma unroll
      for (int i = 0; i < 4; ++i)
#pragma unroll
        for (int j = 0; j < 4; ++j)
          acc[i][j] = __builtin_amdgcn_mfma_f32_16x16x32_bf16(af[i], bfr[j], acc[i][j], 0, 0, 0);
    }
    __syncthreads();          // next buf staged AND this buf's reads drained
    cur ^= 1;
  }

  if (n0 < 2048) {   // u columns (block-uniform)
#pragma unroll
    for (int j = 0; j < 4; ++j) {
      int col = n0 + wn * 64 + j * 16 + ml;
      float bias = in_b[col];
      float gam = expf(gamma_log[col >> 1]);
#pragma unroll
      for (int i = 0; i < 4; ++i) {
        int trow = m0 + wm * 64 + i * 16 + q * 4;
#pragma unroll
        for (int v = 0; v < 4; ++v)
          U16[(size_t)(trow + v) * 2048 + col] = bf_rne(gam * (acc[i][j][v] + bias));
      }
    }
  } else {           // nu columns
#pragma unroll
    for (int j = 0; j < 4; ++j) {
      int col = n0 + wn * 64 + j * 16 + ml;
      int c2 = col - 2048;
      float bias = nu_b[c2];
#pragma unroll
      for (int i = 0; i < 4; ++i) {
        int trow = m0 + wm * 64 + i * 16 + q * 4;
#pragma unroll
        for (int v = 0; v < 4; ++v) {
          float z = acc[i][j][v] + bias;
          NU[(size_t)(trow + v) * 1024 + c2] = (_Float16)(1.f / (1.f + expf(-z)));
        }
      }
    }
  }
}

// ---------------------------------------------------------------------------
// Scan phase 1: per (chunk c, batch b, channel dch) local scan from h=0.
// Emits (A_r, A_i, hend_r, hend_i), A = prod of lambda over the chunk.
// ---------------------------------------------------------------------------
__global__ __launch_bounds__(256) void scan_p1_kernel(
    const unsigned short* __restrict__ U16, const _Float16* __restrict__ NU,
    const float* __restrict__ theta_log,
    float* __restrict__ chunkA) {
  int s = blockIdx.x * 256 + threadIdx.x;   // ((c*BB)+b)*DD + dch
  int dch = s & (DD - 1);
  int b = (s >> 10) & (BB - 1);
  int c = s >> 12;
  float theta = expf(theta_log[dch]);
  float ct = cosf(theta), st = sinf(theta);
  float hr = 0.f, hi = 0.f, Ar = 1.f, Ai = 0.f;
  for (int i = 0; i < CL; ++i) {
    int t = (c * CL + i) * 4 + b;
    ushort2 up = *(const ushort2*)(U16 + (size_t)t * 2048 + 2 * dch);
    float ur = bf_to_f(up.x), ui = bf_to_f(up.y);
    float nu = (float)NU[(size_t)t * 1024 + dch];
    float lr = nu * ct, li = nu * st;
    float hr2 = lr * hr - li * hi + ur;
    float hi2 = lr * hi + li * hr + ui;
    hr = hr2; hi = hi2;
    float Ar2 = lr * Ar - li * Ai;
    float Ai2 = lr * Ai + li * Ar;
    Ar = Ar2; Ai = Ai2;
  }
  float4 o = {Ar, Ai, hr, hi};
  *(float4*)(chunkA + (size_t)s * 4) = o;
}

// ---------------------------------------------------------------------------
// Scan phase 2: compose NC chunk summaries per channel; overwrite each
// entry's (z,w) slots in-place with that chunk's carry-in state.
// ---------------------------------------------------------------------------
__global__ __launch_bounds__(256) void scan_p2_kernel(
    float* __restrict__ chunkA) {
  int qx = blockIdx.x * 256 + threadIdx.x;   // b*DD + dch
  int dch = qx & (DD - 1);
  int b = qx >> 10;
  float cr = 0.f, ci = 0.f;
  for (int c = 0; c < NC; ++c) {
    size_t idx = ((size_t)(c * BB + b) * DD + dch) * 4;
    float4 v = *(const float4*)(chunkA + idx);
    float2 wv = {cr, ci};
    *(float2*)(chunkA + idx + 2) = wv;      // carry-in for chunk c
    float nr = v.x * cr - v.y * ci + v.z;
    float ni = v.x * ci + v.y * cr + v.w;
    cr = nr; ci = ni;
  }
}

// ---------------------------------------------------------------------------
// Scan phase 3: block per (c,b); re-run chunk from carry-in; overwrite u
// bf16 pairs IN-PLACE with feature bf16 pairs: U16[t][2d]=bf16(h_r[d]),
// U16[t][2d+1]=bf16(h_i[d]). Each thread reads and writes the SAME 16 bytes
// (channels 4*tid..4*tid+3) -> no __syncthreads needed, pure streaming.
// ---------------------------------------------------------------------------
__global__ __launch_bounds__(256) void scan_p3_kernel(
    unsigned short* __restrict__ U16, const _Float16* __restrict__ NU,
    const float* __restrict__ theta_log, const float* __restrict__ chunkA) {
  const int c = blockIdx.x >> 2, b = blockIdx.x & 3;
  const int tid = threadIdx.x;
  float ct[4], st[4], hr[4], hi_[4];
#pragma unroll
  for (int dj = 0; dj < 4; ++dj) {
    int d = tid * 4 + dj;
    float th = expf(theta_log[d]);
    ct[dj] = cosf(th); st[dj] = sinf(th);
    const float* cp = chunkA + ((size_t)((c * 4 + b) * 1024) + d) * 4 + 2;
    hr[dj] = cp[0]; hi_[dj] = cp[1];
  }
  for (int i = 0; i < CL; ++i) {
    int t = (c * CL + i) * 4 + b;
    unsigned short* up = U16 + (size_t)t * 2048 + 8 * tid;
    bf16x8 uv = *(const bf16x8*)up;
    const _Float16* nup = NU + (size_t)t * 1024 + 4 * tid;
    bf16x8 fo;
#pragma unroll
    for (int dj = 0; dj < 4; ++dj) {
      float nu = (float)nup[dj];
      float lr = nu * ct[dj], li = nu * st[dj];
      float nhr = lr * hr[dj] - li * hi_[dj] + bf_to_f((unsigned short)uv[2 * dj]);
      float nhi = lr * hi_[dj] + li * hr[dj] + bf_to_f((unsigned short)uv[2 * dj + 1]);
      hr[dj] = nhr; hi_[dj] = nhi;
      fo[2 * dj] = (short)bf_rne(nhr);
      fo[2 * dj + 1] = (short)bf_rne(nhi);
    }
    *(bf16x8*)up = fo;
  }
}

// ---------------------------------------------------------------------------
// GEMM2 (MFMA): out[t][j] = F[t,:] . W2[j,:] + out_b[j], K=2048 bf16, BK=64.
// F = U16 after scan_p3 (contiguous rows, stride 2048 shorts).
// Same 2-phase LDS double-buffer as gemm1.
// ---------------------------------------------------------------------------
__global__ __launch_bounds__(256, 2) void gemm2_mfma(
    const unsigned short* __restrict__ F,
    const unsigned short* __restrict__ W2,
    const float* __restrict__ out_b,
    float* __restrict__ out) {
  __shared__ unsigned short As[2][8192];
  __shared__ unsigned short Bs[2][8192];
  const int tid = threadIdx.x;
  const int w = tid >> 6, l = tid & 63;
  const int q = l >> 4, ml = l & 15;
  const int m0 = blockIdx.y * 128;
  const int n0 = blockIdx.x * 128;
  const int wm = w & 1, wn = w >> 1;

  f32x4 acc[4][4] = {};

  auto stage = [&](int p, int k0) {
#pragma unroll
    for (int h = 0; h < 2; ++h) {
      int kq = 2 * w + h;
      async16(F + (size_t)(m0 + l) * 2048 + k0 + kq * 8, &As[p][(kq * 128) * 8]);
      async16(F + (size_t)(m0 + 64 + l) * 2048 + k0 + kq * 8, &As[p][(kq * 128 + 64) * 8]);
      async16(W2 + (size_t)(n0 + l) * 2048 + k0 + kq * 8, &Bs[p][(kq * 128) * 8]);
      async16(W2 + (size_t)(n0 + 64 + l) * 2048 + k0 + kq * 8, &Bs[p][(kq * 128 + 64) * 8]);
    }
  };

  stage(0, 0);
  __syncthreads();
  int cur = 0;
  for (int k0 = 0; k0 < 2048; k0 += 64) {
    if (k0 + 64 < 2048) stage(cur ^ 1, k0 + 64);
#pragma unroll
    for (int s = 0; s < 2; ++s) {
      bf16x8 af[4], bfr[4];
#pragma unroll
      for (int i = 0; i < 4; ++i)
        af[i] = *(const bf16x8*)&As[cur][(((s * 4 + q) * 128) + wm * 64 + i * 16 + ml) * 8];
#pragma unroll
      for (int j = 0; j < 4; ++j)
        bfr[j] = *(const bf16x8*)&Bs[cur][(((s * 4 + q) * 128) + wn * 64 + j * 16 + ml) * 8];
#pragma unroll
      for (int i = 0; i < 4; ++i)
#pragma unroll
        for (int j = 0; j < 4; ++j)
          acc[i][j] = __builtin_amdgcn_mfma_f32_16x16x32_bf16(af[i], bfr[j], acc[i][j], 0, 0, 0);
    }
    __syncthreads();
    cur ^= 1;
  }

#pragma unroll
  for (int j = 0; j < 4; ++j) {
    int col = n0 + wn * 64 + j * 16 + ml;
    float bias = out_b[col];
#pragma unroll
    for (int i = 0; i < 4; ++i) {
      int trow = m0 + wm * 64 + i * 16 + q * 4;
#pragma unroll
      for (int v = 0; v < 4; ++v) {
        int t = trow + v;
        out[((size_t)(t & 3) * NN + (t >> 2)) * DD + col] = acc[i][j][v] + bias;
      }
    }
  }
}

extern "C" void kernel_launch(void* const* d_in, const int* in_sizes, int n_in,
                              void* d_out, int out_size, void* d_ws, size_t ws_size,
                              hipStream_t stream) {
  const float* x         = (const float*)d_in[0];
  const float* theta_log = (const float*)d_in[1];
  const float* gamma_log = (const float*)d_in[2];
  const float* nu_w      = (const float*)d_in[3];
  const float* nu_b      = (const float*)d_in[4];
  const float* in_w      = (const float*)d_in[5];
  const float* in_b      = (const float*)d_in[6];
  const float* out_w     = (const float*)d_in[7];
  const float* out_b     = (const float*)d_in[8];
  float* out = (float*)d_out;

  // Workspace layout: 148,897,792 B total (round 0 proved ws_size >= 216 MB)
  char* base = (char*)d_ws;
  unsigned short* U16 = (unsigned short*)base;                 //  67,108,864
  _Float16*       NU  = (_Float16*)(base + 67108864);          //  33,554,432
  unsigned short* Abf = (unsigned short*)(base + 100663296);   //  33,554,432
  unsigned short* W1  = (unsigned short*)(base + 134217728);   //   6,291,456
  unsigned short* W2  = (unsigned short*)(base + 140509184);   //   4,194,304
  float*          chunkA = (float*)(base + 144703488);         //   4,194,304

  conv_x_kernel<<<(BB * NN * DD) / 256, 256, 0, stream>>>(x, Abf);
  conv_w1_kernel<<<(3072 * 1024) / 256, 256, 0, stream>>>(in_w, nu_w, W1);
  conv_w2_kernel<<<(1024 * 1024) / 256, 256, 0, stream>>>(out_w, W2);
  gemm1_mfma<<<dim3(3072 / 128, TT / 128), 256, 0, stream>>>(
      Abf, W1, in_b, nu_b, gamma_log, U16, NU);
  scan_p1_kernel<<<(NC * BB * DD) / 256, 256, 0, stream>>>(U16, NU, theta_log, chunkA);
  scan_p2_kernel<<<(BB * DD) / 256, 256, 0, stream>>>(chunkA);
  scan_p3_kernel<<<NC * BB, 256, 0, stream>>>(U16, NU, theta_log, chunkA);
  gemm2_mfma<<<dim3(1024 / 128, TT / 128), 256, 0, stream>>>(U16, W2, out_b, out);
}

// Round 2
// 570.890 us; speedup vs baseline: 1.0365x; 1.0365x over previous
//
#include <hip/hip_runtime.h>
#include <math.h>
#include <stdint.h>

#define BB 4
#define NN 4096
#define DD 1024
#define TT (BB * NN)          // 16384 tokens
#define NC 64                 // scan chunks
#define CL (NN / NC)          // 64 steps per chunk

typedef __attribute__((ext_vector_type(8))) short bf16x8;
typedef __attribute__((ext_vector_type(4))) float f32x4;

// bf16 round-to-nearest-even (returns top-16 bit pattern)
__device__ inline unsigned short bf_rne(float v) {
  union { float f; uint32_t u; } x; x.f = v;
  uint32_t r = x.u + 0x7fffu + ((x.u >> 16) & 1u);
  return (unsigned short)(r >> 16);
}
__device__ inline float bf_to_f(unsigned short h) {
  union { float f; uint32_t u; } x; x.u = ((uint32_t)h) << 16;
  return x.f;
}

// async global->LDS, 16 bytes per lane, deposits at (wave-uniform base + lane*16)
__device__ inline void async16(const void* g, void* l) {
  __builtin_amdgcn_global_load_lds(
      (const __attribute__((address_space(1))) uint32_t*)g,
      (__attribute__((address_space(3))) uint32_t*)l, 16, 0, 0);
}

// ---------------------------------------------------------------------------
// conv_x: x (b,n,d) fp32 -> Abf (t = n*4+b, 1024) bf16
// ---------------------------------------------------------------------------
__global__ __launch_bounds__(256) void conv_x_kernel(
    const float* __restrict__ x, unsigned short* __restrict__ Abf) {
  int idx = blockIdx.x * 256 + threadIdx.x;     // over BB*NN*DD
  int k = idx & 1023;
  int n = (idx >> 10) & 4095;
  int b = idx >> 22;
  Abf[(size_t)(n * 4 + b) * 1024 + k] = bf_rne(x[idx]);
}

// ---------------------------------------------------------------------------
// conv_w1: rows [in_w(2048); nu_w(1024)] (e,1024) fp32 -> W1 bf16
// ---------------------------------------------------------------------------
__global__ __launch_bounds__(256) void conv_w1_kernel(
    const float* __restrict__ in_w, const float* __restrict__ nu_w,
    unsigned short* __restrict__ W1) {
  int idx = blockIdx.x * 256 + threadIdx.x;     // over 3072*1024
  float v = (idx < 2048 * 1024) ? in_w[idx] : nu_w[idx - 2048 * 1024];
  W1[idx] = bf_rne(v);
}

// ---------------------------------------------------------------------------
// conv_w2: out_w (j, 2048) fp32 -> W2 (j, 2048) bf16, (r,i)-interleaved:
// W2[j][2d] = out_w[j][d], W2[j][2d+1] = out_w[j][1024+d]
// ---------------------------------------------------------------------------
__global__ __launch_bounds__(256) void conv_w2_kernel(
    const float* __restrict__ out_w, unsigned short* __restrict__ W2) {
  int idx = blockIdx.x * 256 + threadIdx.x;     // over 1024*1024
  int j = idx >> 10, d = idx & 1023;
  W2[(size_t)j * 2048 + 2 * d]     = bf_rne(out_w[(size_t)j * 2048 + d]);
  W2[(size_t)j * 2048 + 2 * d + 1] = bf_rne(out_w[(size_t)j * 2048 + 1024 + d]);
}

// ---------------------------------------------------------------------------
// GEMM1 (MFMA): z = Abf[t,:] . W1[e,:], K=1024 bf16. 128x128 tile, BK=64,
// 4 waves, each 4x4 of 16x16x32 MFMA.
// Round-6 change: COUNTED vmcnt + RAW s_barrier (T4). Round-1 post-mortem:
// __syncthreads drains vmcnt(0) -> prefetch gave zero overlap. Now each wave
// issues next buffer's 8 global_load_lds, then waits vmcnt(8) (= current
// buffer's 8 loads retired, in-order), raw s_barrier, compute. The 8
// prefetch loads stay IN FLIGHT under the MFMA block and are only waited
// one K-step later. Never vmcnt(0) inside the loop.
// Epilogue:
//   e < 2048 : U16[t,e]  = bf16( gamma[e>>1]*(z + in_b[e]) )   (u interleaved)
//   e >= 2048: NU[t,e']  = fp16( sigmoid(z + nu_b[e']) )
// ---------------------------------------------------------------------------
__global__ __launch_bounds__(256, 2) void gemm1_mfma(
    const unsigned short* __restrict__ A,
    const unsigned short* __restrict__ W1,
    const float* __restrict__ in_b, const float* __restrict__ nu_b,
    const float* __restrict__ gamma_log,
    unsigned short* __restrict__ U16, _Float16* __restrict__ NU) {
  __shared__ unsigned short As[2][8192];   // 2 x 16 KB
  __shared__ unsigned short Bs[2][8192];   // 2 x 16 KB
  const int tid = threadIdx.x;
  const int w = tid >> 6, l = tid & 63;
  const int q = l >> 4, ml = l & 15;
  const int m0 = blockIdx.y * 128;
  const int n0 = blockIdx.x * 128;
  const int wm = w & 1, wn = w >> 1;

  f32x4 acc[4][4] = {};

  auto stage = [&](int p, int k0) {
#pragma unroll
    for (int h = 0; h < 2; ++h) {
      int kq = 2 * w + h;     // wave w stages kq slices 2w, 2w+1 (8 loads/wave)
      async16(A + (size_t)(m0 + l) * 1024 + k0 + kq * 8, &As[p][(kq * 128) * 8]);
      async16(A + (size_t)(m0 + 64 + l) * 1024 + k0 + kq * 8, &As[p][(kq * 128 + 64) * 8]);
      async16(W1 + (size_t)(n0 + l) * 1024 + k0 + kq * 8, &Bs[p][(kq * 128) * 8]);
      async16(W1 + (size_t)(n0 + 64 + l) * 1024 + k0 + kq * 8, &Bs[p][(kq * 128 + 64) * 8]);
    }
  };

  stage(0, 0);                // 8 loads in flight
  int cur = 0;
  for (int k0 = 0; k0 < 1024; k0 += 64) {
    if (k0 + 64 < 1024) {
      stage(cur ^ 1, k0 + 64);                       // +8 loads (16 outstanding)
      asm volatile("s_waitcnt vmcnt(8)" ::: "memory");  // cur buffer's 8 done
    } else {
      asm volatile("s_waitcnt vmcnt(0)" ::: "memory");  // epilogue drain
    }
    __builtin_amdgcn_s_barrier();        // raw: no implicit vmcnt(0) drain
    __builtin_amdgcn_sched_barrier(0);   // keep ds_reads below the barrier
#pragma unroll
    for (int s = 0; s < 2; ++s) {
      bf16x8 af[4], bfr[4];
#pragma unroll
      for (int i = 0; i < 4; ++i)
        af[i] = *(const bf16x8*)&As[cur][(((s * 4 + q) * 128) + wm * 64 + i * 16 + ml) * 8];
#pragma unroll
      for (int j = 0; j < 4; ++j)
        bfr[j] = *(const bf16x8*)&Bs[cur][(((s * 4 + q) * 128) + wn * 64 + j * 16 + ml) * 8];
#pragma unroll
      for (int i = 0; i < 4; ++i)
#pragma unroll
        for (int j = 0; j < 4; ++j)
          acc[i][j] = __builtin_amdgcn_mfma_f32_16x16x32_bf16(af[i], bfr[j], acc[i][j], 0, 0, 0);
    }
    __builtin_amdgcn_sched_barrier(0);   // ds_reads consumed before barrier
    __builtin_amdgcn_s_barrier();        // all waves done reading buf[cur]
    cur ^= 1;
  }

  if (n0 < 2048) {   // u columns (block-uniform)
#pragma unroll
    for (int j = 0; j < 4; ++j) {
      int col = n0 + wn * 64 + j * 16 + ml;
      float bias = in_b[col];
      float gam = expf(gamma_log[col >> 1]);
#pragma unroll
      for (int i = 0; i < 4; ++i) {
        int trow = m0 + wm * 64 + i * 16 + q * 4;
#pragma unroll
        for (int v = 0; v < 4; ++v)
          U16[(size_t)(trow + v) * 2048 + col] = bf_rne(gam * (acc[i][j][v] + bias));
      }
    }
  } else {           // nu columns
#pragma unroll
    for (int j = 0; j < 4; ++j) {
      int col = n0 + wn * 64 + j * 16 + ml;
      int c2 = col - 2048;
      float bias = nu_b[c2];
#pragma unroll
      for (int i = 0; i < 4; ++i) {
        int trow = m0 + wm * 64 + i * 16 + q * 4;
#pragma unroll
        for (int v = 0; v < 4; ++v) {
          float z = acc[i][j][v] + bias;
          NU[(size_t)(trow + v) * 1024 + c2] = (_Float16)(1.f / (1.f + expf(-z)));
        }
      }
    }
  }
}

// ---------------------------------------------------------------------------
// Scan phase 1: per (chunk c, batch b, channel dch) local scan from h=0.
// Emits (A_r, A_i, hend_r, hend_i), A = prod of lambda over the chunk.
// ---------------------------------------------------------------------------
__global__ __launch_bounds__(256) void scan_p1_kernel(
    const unsigned short* __restrict__ U16, const _Float16* __restrict__ NU,
    const float* __restrict__ theta_log,
    float* __restrict__ chunkA) {
  int s = blockIdx.x * 256 + threadIdx.x;   // ((c*BB)+b)*DD + dch
  int dch = s & (DD - 1);
  int b = (s >> 10) & (BB - 1);
  int c = s >> 12;
  float theta = expf(theta_log[dch]);
  float ct = cosf(theta), st = sinf(theta);
  float hr = 0.f, hi = 0.f, Ar = 1.f, Ai = 0.f;
  for (int i = 0; i < CL; ++i) {
    int t = (c * CL + i) * 4 + b;
    ushort2 up = *(const ushort2*)(U16 + (size_t)t * 2048 + 2 * dch);
    float ur = bf_to_f(up.x), ui = bf_to_f(up.y);
    float nu = (float)NU[(size_t)t * 1024 + dch];
    float lr = nu * ct, li = nu * st;
    float hr2 = lr * hr - li * hi + ur;
    float hi2 = lr * hi + li * hr + ui;
    hr = hr2; hi = hi2;
    float Ar2 = lr * Ar - li * Ai;
    float Ai2 = lr * Ai + li * Ar;
    Ar = Ar2; Ai = Ai2;
  }
  float4 o = {Ar, Ai, hr, hi};
  *(float4*)(chunkA + (size_t)s * 4) = o;
}

// ---------------------------------------------------------------------------
// Scan phase 2: compose NC chunk summaries per channel; overwrite each
// entry's (z,w) slots in-place with that chunk's carry-in state.
// ---------------------------------------------------------------------------
__global__ __launch_bounds__(256) void scan_p2_kernel(
    float* __restrict__ chunkA) {
  int qx = blockIdx.x * 256 + threadIdx.x;   // b*DD + dch
  int dch = qx & (DD - 1);
  int b = qx >> 10;
  float cr = 0.f, ci = 0.f;
  for (int c = 0; c < NC; ++c) {
    size_t idx = ((size_t)(c * BB + b) * DD + dch) * 4;
    float4 v = *(const float4*)(chunkA + idx);
    float2 wv = {cr, ci};
    *(float2*)(chunkA + idx + 2) = wv;      // carry-in for chunk c
    float nr = v.x * cr - v.y * ci + v.z;
    float ni = v.x * ci + v.y * cr + v.w;
    cr = nr; ci = ni;
  }
}

// ---------------------------------------------------------------------------
// Scan phase 3: block per (c,b); re-run chunk from carry-in; overwrite u
// bf16 pairs IN-PLACE with feature bf16 pairs: U16[t][2d]=bf16(h_r[d]),
// U16[t][2d+1]=bf16(h_i[d]). Each thread reads and writes the SAME 16 bytes
// (channels 4*tid..4*tid+3) -> no __syncthreads needed, pure streaming.
// ---------------------------------------------------------------------------
__global__ __launch_bounds__(256) void scan_p3_kernel(
    unsigned short* __restrict__ U16, const _Float16* __restrict__ NU,
    const float* __restrict__ theta_log, const float* __restrict__ chunkA) {
  const int c = blockIdx.x >> 2, b = blockIdx.x & 3;
  const int tid = threadIdx.x;
  float ct[4], st[4], hr[4], hi_[4];
#pragma unroll
  for (int dj = 0; dj < 4; ++dj) {
    int d = tid * 4 + dj;
    float th = expf(theta_log[d]);
    ct[dj] = cosf(th); st[dj] = sinf(th);
    const float* cp = chunkA + ((size_t)((c * 4 + b) * 1024) + d) * 4 + 2;
    hr[dj] = cp[0]; hi_[dj] = cp[1];
  }
  for (int i = 0; i < CL; ++i) {
    int t = (c * CL + i) * 4 + b;
    unsigned short* up = U16 + (size_t)t * 2048 + 8 * tid;
    bf16x8 uv = *(const bf16x8*)up;
    const _Float16* nup = NU + (size_t)t * 1024 + 4 * tid;
    bf16x8 fo;
#pragma unroll
    for (int dj = 0; dj < 4; ++dj) {
      float nu = (float)nup[dj];
      float lr = nu * ct[dj], li = nu * st[dj];
      float nhr = lr * hr[dj] - li * hi_[dj] + bf_to_f((unsigned short)uv[2 * dj]);
      float nhi = lr * hi_[dj] + li * hr[dj] + bf_to_f((unsigned short)uv[2 * dj + 1]);
      hr[dj] = nhr; hi_[dj] = nhi;
      fo[2 * dj] = (short)bf_rne(nhr);
      fo[2 * dj + 1] = (short)bf_rne(nhi);
    }
    *(bf16x8*)up = fo;
  }
}

// ---------------------------------------------------------------------------
// GEMM2 (MFMA): out[t][j] = F[t,:] . W2[j,:] + out_b[j], K=2048 bf16, BK=64.
// F = U16 after scan_p3 (contiguous rows, stride 2048 shorts).
// Same counted-vmcnt + raw-barrier pipeline as gemm1.
// ---------------------------------------------------------------------------
__global__ __launch_bounds__(256, 2) void gemm2_mfma(
    const unsigned short* __restrict__ F,
    const unsigned short* __restrict__ W2,
    const float* __restrict__ out_b,
    float* __restrict__ out) {
  __shared__ unsigned short As[2][8192];
  __shared__ unsigned short Bs[2][8192];
  const int tid = threadIdx.x;
  const int w = tid >> 6, l = tid & 63;
  const int q = l >> 4, ml = l & 15;
  const int m0 = blockIdx.y * 128;
  const int n0 = blockIdx.x * 128;
  const int wm = w & 1, wn = w >> 1;

  f32x4 acc[4][4] = {};

  auto stage = [&](int p, int k0) {
#pragma unroll
    for (int h = 0; h < 2; ++h) {
      int kq = 2 * w + h;
      async16(F + (size_t)(m0 + l) * 2048 + k0 + kq * 8, &As[p][(kq * 128) * 8]);
      async16(F + (size_t)(m0 + 64 + l) * 2048 + k0 + kq * 8, &As[p][(kq * 128 + 64) * 8]);
      async16(W2 + (size_t)(n0 + l) * 2048 + k0 + kq * 8, &Bs[p][(kq * 128) * 8]);
      async16(W2 + (size_t)(n0 + 64 + l) * 2048 + k0 + kq * 8, &Bs[p][(kq * 128 + 64) * 8]);
    }
  };

  stage(0, 0);
  int cur = 0;
  for (int k0 = 0; k0 < 2048; k0 += 64) {
    if (k0 + 64 < 2048) {
      stage(cur ^ 1, k0 + 64);
      asm volatile("s_waitcnt vmcnt(8)" ::: "memory");
    } else {
      asm volatile("s_waitcnt vmcnt(0)" ::: "memory");
    }
    __builtin_amdgcn_s_barrier();
    __builtin_amdgcn_sched_barrier(0);
#pragma unroll
    for (int s = 0; s < 2; ++s) {
      bf16x8 af[4], bfr[4];
#pragma unroll
      for (int i = 0; i < 4; ++i)
        af[i] = *(const bf16x8*)&As[cur][(((s * 4 + q) * 128) + wm * 64 + i * 16 + ml) * 8];
#pragma unroll
      for (int j = 0; j < 4; ++j)
        bfr[j] = *(const bf16x8*)&Bs[cur][(((s * 4 + q) * 128) + wn * 64 + j * 16 + ml) * 8];
#pragma unroll
      for (int i = 0; i < 4; ++i)
#pragma unroll
        for (int j = 0; j < 4; ++j)
          acc[i][j] = __builtin_amdgcn_mfma_f32_16x16x32_bf16(af[i], bfr[j], acc[i][j], 0, 0, 0);
    }
    __builtin_amdgcn_sched_barrier(0);
    __builtin_amdgcn_s_barrier();
    cur ^= 1;
  }

#pragma unroll
  for (int j = 0; j < 4; ++j) {
    int col = n0 + wn * 64 + j * 16 + ml;
    float bias = out_b[col];
#pragma unroll
    for (int i = 0; i < 4; ++i) {
      int trow = m0 + wm * 64 + i * 16 + q * 4;
#pragma unroll
      for (int v = 0; v < 4; ++v) {
        int t = trow + v;
        out[((size_t)(t & 3) * NN + (t >> 2)) * DD + col] = acc[i][j][v] + bias;
      }
    }
  }
}

extern "C" void kernel_launch(void* const* d_in, const int* in_sizes, int n_in,
                              void* d_out, int out_size, void* d_ws, size_t ws_size,
                              hipStream_t stream) {
  const float* x         = (const float*)d_in[0];
  const float* theta_log = (const float*)d_in[1];
  const float* gamma_log = (const float*)d_in[2];
  const float* nu_w      = (const float*)d_in[3];
  const float* nu_b      = (const float*)d_in[4];
  const float* in_w      = (const float*)d_in[5];
  const float* in_b      = (const float*)d_in[6];
  const float* out_w     = (const float*)d_in[7];
  const float* out_b     = (const float*)d_in[8];
  float* out = (float*)d_out;

  // Workspace layout: 148,897,792 B total (round 0 proved ws_size >= 216 MB)
  char* base = (char*)d_ws;
  unsigned short* U16 = (unsigned short*)base;                 //  67,108,864
  _Float16*       NU  = (_Float16*)(base + 67108864);          //  33,554,432
  unsigned short* Abf = (unsigned short*)(base + 100663296);   //  33,554,432
  unsigned short* W1  = (unsigned short*)(base + 134217728);   //   6,291,456
  unsigned short* W2  = (unsigned short*)(base + 140509184);   //   4,194,304
  float*          chunkA = (float*)(base + 144703488);         //   4,194,304

  conv_x_kernel<<<(BB * NN * DD) / 256, 256, 0, stream>>>(x, Abf);
  conv_w1_kernel<<<(3072 * 1024) / 256, 256, 0, stream>>>(in_w, nu_w, W1);
  conv_w2_kernel<<<(1024 * 1024) / 256, 256, 0, stream>>>(out_w, W2);
  gemm1_mfma<<<dim3(3072 / 128, TT / 128), 256, 0, stream>>>(
      Abf, W1, in_b, nu_b, gamma_log, U16, NU);
  scan_p1_kernel<<<(NC * BB * DD) / 256, 256, 0, stream>>>(U16, NU, theta_log, chunkA);
  scan_p2_kernel<<<(BB * DD) / 256, 256, 0, stream>>>(chunkA);
  scan_p3_kernel<<<NC * BB, 256, 0, stream>>>(U16, NU, theta_log, chunkA);
  gemm2_mfma<<<dim3(1024 / 128, TT / 128), 256, 0, stream>>>(U16, W2, out_b, out);
}

// Round 3
// 511.869 us; speedup vs baseline: 1.1560x; 1.1153x over previous
//
#include <hip/hip_runtime.h>
#include <math.h>
#include <stdint.h>

#define BB 4
#define NN 4096
#define DD 1024
#define TT (BB * NN)          // 16384 tokens
#define NC 64                 // scan chunks
#define CL (NN / NC)          // 64 steps per chunk

typedef __attribute__((ext_vector_type(8))) short bf16x8;
typedef __attribute__((ext_vector_type(4))) float f32x4;

// bf16 round-to-nearest-even (returns top-16 bit pattern)
__device__ inline unsigned short bf_rne(float v) {
  union { float f; uint32_t u; } x; x.f = v;
  uint32_t r = x.u + 0x7fffu + ((x.u >> 16) & 1u);
  return (unsigned short)(r >> 16);
}
__device__ inline float bf_to_f(unsigned short h) {
  union { float f; uint32_t u; } x; x.u = ((uint32_t)h) << 16;
  return x.f;
}

// async global->LDS, 16 bytes per lane, deposits at (wave-uniform base + lane*16)
__device__ inline void async16(const void* g, void* l) {
  __builtin_amdgcn_global_load_lds(
      (const __attribute__((address_space(1))) uint32_t*)g,
      (__attribute__((address_space(3))) uint32_t*)l, 16, 0, 0);
}

// ---------------------------------------------------------------------------
// conv_x: x (b,n,d) fp32 -> Abf (t = n*4+b, 1024) bf16
// ---------------------------------------------------------------------------
__global__ __launch_bounds__(256) void conv_x_kernel(
    const float* __restrict__ x, unsigned short* __restrict__ Abf) {
  int idx = blockIdx.x * 256 + threadIdx.x;     // over BB*NN*DD
  int k = idx & 1023;
  int n = (idx >> 10) & 4095;
  int b = idx >> 22;
  Abf[(size_t)(n * 4 + b) * 1024 + k] = bf_rne(x[idx]);
}

// ---------------------------------------------------------------------------
// conv_w1: rows [in_w(2048); nu_w(1024)] (e,1024) fp32 -> W1 bf16
// ---------------------------------------------------------------------------
__global__ __launch_bounds__(256) void conv_w1_kernel(
    const float* __restrict__ in_w, const float* __restrict__ nu_w,
    unsigned short* __restrict__ W1) {
  int idx = blockIdx.x * 256 + threadIdx.x;     // over 3072*1024
  float v = (idx < 2048 * 1024) ? in_w[idx] : nu_w[idx - 2048 * 1024];
  W1[idx] = bf_rne(v);
}

// ---------------------------------------------------------------------------
// conv_w2: out_w (j, 2048) fp32 -> W2 (j, 2048) bf16, (r,i)-interleaved:
// W2[j][2d] = out_w[j][d], W2[j][2d+1] = out_w[j][1024+d]
// ---------------------------------------------------------------------------
__global__ __launch_bounds__(256) void conv_w2_kernel(
    const float* __restrict__ out_w, unsigned short* __restrict__ W2) {
  int idx = blockIdx.x * 256 + threadIdx.x;     // over 1024*1024
  int j = idx >> 10, d = idx & 1023;
  W2[(size_t)j * 2048 + 2 * d]     = bf_rne(out_w[(size_t)j * 2048 + d]);
  W2[(size_t)j * 2048 + 2 * d + 1] = bf_rne(out_w[(size_t)j * 2048 + 1024 + d]);
}

// ---------------------------------------------------------------------------
// GEMM1 (MFMA): z = Abf[t,:] . W1[e,:], K=1024 bf16.
// Round-7 change: 256x256 tile, BK=64, 8 waves (2M x 4N), 512 threads.
// Same verified counted-vmcnt + raw-barrier 2-phase as round 2, but 2x the
// MFMA work per staged byte (512 MFMA vs 64 KB staging per K-step).
// LDS 128 KiB (2 dbuf x 32 KB x {A,B}), 1 block/CU, kq-major layout
// (conflict-free, SQ_LDS_BANK_CONFLICT=0 measured). acc[8][4] f32x4.
// Each wave: rows [wm*128,+128), cols [wn*64,+64). Wave w stages kq=w.
// Epilogue:
//   e < 2048 : U16[t,e]  = bf16( gamma[e>>1]*(z + in_b[e]) )   (u interleaved)
//   e >= 2048: NU[t,e']  = fp16( sigmoid(z + nu_b[e']) )
// N split at n0=2048 stays block-uniform (2048/256 = 8 tiles).
// ---------------------------------------------------------------------------
__global__ __launch_bounds__(512, 2) void gemm1_mfma(
    const unsigned short* __restrict__ A,
    const unsigned short* __restrict__ W1,
    const float* __restrict__ in_b, const float* __restrict__ nu_b,
    const float* __restrict__ gamma_log,
    unsigned short* __restrict__ U16, _Float16* __restrict__ NU) {
  __shared__ unsigned short As[2][16384];   // 2 x 32 KB
  __shared__ unsigned short Bs[2][16384];   // 2 x 32 KB
  const int tid = threadIdx.x;
  const int w = tid >> 6, l = tid & 63;
  const int q = l >> 4, ml = l & 15;
  const int m0 = blockIdx.y * 256;
  const int n0 = blockIdx.x * 256;
  const int wm = w & 1, wn = w >> 1;        // wm: row half, wn: col quarter

  f32x4 acc[8][4] = {};

  auto stage = [&](int p, int k0) {
#pragma unroll
    for (int rg = 0; rg < 4; ++rg) {        // 4 row-groups of 64; wave stages kq=w
      async16(A  + (size_t)(m0 + rg * 64 + l) * 1024 + k0 + w * 8,
              &As[p][(w * 256 + rg * 64) * 8]);
      async16(W1 + (size_t)(n0 + rg * 64 + l) * 1024 + k0 + w * 8,
              &Bs[p][(w * 256 + rg * 64) * 8]);
    }
  };

  stage(0, 0);                // 8 loads/wave in flight
  int cur = 0;
  for (int k0 = 0; k0 < 1024; k0 += 64) {
    if (k0 + 64 < 1024) {
      stage(cur ^ 1, k0 + 64);                          // +8 (16 outstanding)
      asm volatile("s_waitcnt vmcnt(8)" ::: "memory");  // cur buffer's 8 done
    } else {
      asm volatile("s_waitcnt vmcnt(0)" ::: "memory");  // final drain
    }
    __builtin_amdgcn_s_barrier();        // raw: no implicit vmcnt(0) drain
    __builtin_amdgcn_sched_barrier(0);   // keep ds_reads below the barrier
#pragma unroll
    for (int ks = 0; ks < 2; ++ks) {     // two 32-wide k-slices
      bf16x8 af[8], bfr[4];
#pragma unroll
      for (int i = 0; i < 8; ++i)
        af[i] = *(const bf16x8*)&As[cur][(((ks * 4 + q) * 256) + wm * 128 + i * 16 + ml) * 8];
#pragma unroll
      for (int j = 0; j < 4; ++j)
        bfr[j] = *(const bf16x8*)&Bs[cur][(((ks * 4 + q) * 256) + wn * 64 + j * 16 + ml) * 8];
#pragma unroll
      for (int i = 0; i < 8; ++i)
#pragma unroll
        for (int j = 0; j < 4; ++j)
          acc[i][j] = __builtin_amdgcn_mfma_f32_16x16x32_bf16(af[i], bfr[j], acc[i][j], 0, 0, 0);
    }
    __builtin_amdgcn_sched_barrier(0);   // ds_reads consumed before barrier
    __builtin_amdgcn_s_barrier();        // all waves done reading buf[cur]
    cur ^= 1;
  }

  if (n0 < 2048) {   // u columns (block-uniform)
#pragma unroll
    for (int j = 0; j < 4; ++j) {
      int col = n0 + wn * 64 + j * 16 + ml;
      float bias = in_b[col];
      float gam = expf(gamma_log[col >> 1]);
#pragma unroll
      for (int i = 0; i < 8; ++i) {
        int trow = m0 + wm * 128 + i * 16 + q * 4;
#pragma unroll
        for (int v = 0; v < 4; ++v)
          U16[(size_t)(trow + v) * 2048 + col] = bf_rne(gam * (acc[i][j][v] + bias));
      }
    }
  } else {           // nu columns
#pragma unroll
    for (int j = 0; j < 4; ++j) {
      int col = n0 + wn * 64 + j * 16 + ml;
      int c2 = col - 2048;
      float bias = nu_b[c2];
#pragma unroll
      for (int i = 0; i < 8; ++i) {
        int trow = m0 + wm * 128 + i * 16 + q * 4;
#pragma unroll
        for (int v = 0; v < 4; ++v) {
          float z = acc[i][j][v] + bias;
          NU[(size_t)(trow + v) * 1024 + c2] = (_Float16)(1.f / (1.f + expf(-z)));
        }
      }
    }
  }
}

// ---------------------------------------------------------------------------
// Scan phase 1: per (chunk c, batch b, channel dch) local scan from h=0.
// Emits (A_r, A_i, hend_r, hend_i), A = prod of lambda over the chunk.
// ---------------------------------------------------------------------------
__global__ __launch_bounds__(256) void scan_p1_kernel(
    const unsigned short* __restrict__ U16, const _Float16* __restrict__ NU,
    const float* __restrict__ theta_log,
    float* __restrict__ chunkA) {
  int s = blockIdx.x * 256 + threadIdx.x;   // ((c*BB)+b)*DD + dch
  int dch = s & (DD - 1);
  int b = (s >> 10) & (BB - 1);
  int c = s >> 12;
  float theta = expf(theta_log[dch]);
  float ct = cosf(theta), st = sinf(theta);
  float hr = 0.f, hi = 0.f, Ar = 1.f, Ai = 0.f;
  for (int i = 0; i < CL; ++i) {
    int t = (c * CL + i) * 4 + b;
    ushort2 up = *(const ushort2*)(U16 + (size_t)t * 2048 + 2 * dch);
    float ur = bf_to_f(up.x), ui = bf_to_f(up.y);
    float nu = (float)NU[(size_t)t * 1024 + dch];
    float lr = nu * ct, li = nu * st;
    float hr2 = lr * hr - li * hi + ur;
    float hi2 = lr * hi + li * hr + ui;
    hr = hr2; hi = hi2;
    float Ar2 = lr * Ar - li * Ai;
    float Ai2 = lr * Ai + li * Ar;
    Ar = Ar2; Ai = Ai2;
  }
  float4 o = {Ar, Ai, hr, hi};
  *(float4*)(chunkA + (size_t)s * 4) = o;
}

// ---------------------------------------------------------------------------
// Scan phase 2: compose NC chunk summaries per channel; overwrite each
// entry's (z,w) slots in-place with that chunk's carry-in state.
// ---------------------------------------------------------------------------
__global__ __launch_bounds__(256) void scan_p2_kernel(
    float* __restrict__ chunkA) {
  int qx = blockIdx.x * 256 + threadIdx.x;   // b*DD + dch
  int dch = qx & (DD - 1);
  int b = qx >> 10;
  float cr = 0.f, ci = 0.f;
  for (int c = 0; c < NC; ++c) {
    size_t idx = ((size_t)(c * BB + b) * DD + dch) * 4;
    float4 v = *(const float4*)(chunkA + idx);
    float2 wv = {cr, ci};
    *(float2*)(chunkA + idx + 2) = wv;      // carry-in for chunk c
    float nr = v.x * cr - v.y * ci + v.z;
    float ni = v.x * ci + v.y * cr + v.w;
    cr = nr; ci = ni;
  }
}

// ---------------------------------------------------------------------------
// Scan phase 3: block per (c,b); re-run chunk from carry-in; overwrite u
// bf16 pairs IN-PLACE with feature bf16 pairs: U16[t][2d]=bf16(h_r[d]),
// U16[t][2d+1]=bf16(h_i[d]). Each thread reads and writes the SAME 16 bytes
// (channels 4*tid..4*tid+3) -> no __syncthreads needed, pure streaming.
// ---------------------------------------------------------------------------
__global__ __launch_bounds__(256) void scan_p3_kernel(
    unsigned short* __restrict__ U16, const _Float16* __restrict__ NU,
    const float* __restrict__ theta_log, const float* __restrict__ chunkA) {
  const int c = blockIdx.x >> 2, b = blockIdx.x & 3;
  const int tid = threadIdx.x;
  float ct[4], st[4], hr[4], hi_[4];
#pragma unroll
  for (int dj = 0; dj < 4; ++dj) {
    int d = tid * 4 + dj;
    float th = expf(theta_log[d]);
    ct[dj] = cosf(th); st[dj] = sinf(th);
    const float* cp = chunkA + ((size_t)((c * 4 + b) * 1024) + d) * 4 + 2;
    hr[dj] = cp[0]; hi_[dj] = cp[1];
  }
  for (int i = 0; i < CL; ++i) {
    int t = (c * CL + i) * 4 + b;
    unsigned short* up = U16 + (size_t)t * 2048 + 8 * tid;
    bf16x8 uv = *(const bf16x8*)up;
    const _Float16* nup = NU + (size_t)t * 1024 + 4 * tid;
    bf16x8 fo;
#pragma unroll
    for (int dj = 0; dj < 4; ++dj) {
      float nu = (float)nup[dj];
      float lr = nu * ct[dj], li = nu * st[dj];
      float nhr = lr * hr[dj] - li * hi_[dj] + bf_to_f((unsigned short)uv[2 * dj]);
      float nhi = lr * hi_[dj] + li * hr[dj] + bf_to_f((unsigned short)uv[2 * dj + 1]);
      hr[dj] = nhr; hi_[dj] = nhi;
      fo[2 * dj] = (short)bf_rne(nhr);
      fo[2 * dj + 1] = (short)bf_rne(nhi);
    }
    *(bf16x8*)up = fo;
  }
}

// ---------------------------------------------------------------------------
// GEMM2 (MFMA): out[t][j] = F[t,:] . W2[j,:] + out_b[j], K=2048 bf16, BK=64.
// F = U16 after scan_p3 (contiguous rows, stride 2048 shorts).
// Same 256x256 / 8-wave / counted-vmcnt structure as gemm1. Grid (4,64) =
// 256 blocks = exactly 1 per CU.
// ---------------------------------------------------------------------------
__global__ __launch_bounds__(512, 2) void gemm2_mfma(
    const unsigned short* __restrict__ F,
    const unsigned short* __restrict__ W2,
    const float* __restrict__ out_b,
    float* __restrict__ out) {
  __shared__ unsigned short As[2][16384];
  __shared__ unsigned short Bs[2][16384];
  const int tid = threadIdx.x;
  const int w = tid >> 6, l = tid & 63;
  const int q = l >> 4, ml = l & 15;
  const int m0 = blockIdx.y * 256;
  const int n0 = blockIdx.x * 256;
  const int wm = w & 1, wn = w >> 1;

  f32x4 acc[8][4] = {};

  auto stage = [&](int p, int k0) {
#pragma unroll
    for (int rg = 0; rg < 4; ++rg) {
      async16(F  + (size_t)(m0 + rg * 64 + l) * 2048 + k0 + w * 8,
              &As[p][(w * 256 + rg * 64) * 8]);
      async16(W2 + (size_t)(n0 + rg * 64 + l) * 2048 + k0 + w * 8,
              &Bs[p][(w * 256 + rg * 64) * 8]);
    }
  };

  stage(0, 0);
  int cur = 0;
  for (int k0 = 0; k0 < 2048; k0 += 64) {
    if (k0 + 64 < 2048) {
      stage(cur ^ 1, k0 + 64);
      asm volatile("s_waitcnt vmcnt(8)" ::: "memory");
    } else {
      asm volatile("s_waitcnt vmcnt(0)" ::: "memory");
    }
    __builtin_amdgcn_s_barrier();
    __builtin_amdgcn_sched_barrier(0);
#pragma unroll
    for (int ks = 0; ks < 2; ++ks) {
      bf16x8 af[8], bfr[4];
#pragma unroll
      for (int i = 0; i < 8; ++i)
        af[i] = *(const bf16x8*)&As[cur][(((ks * 4 + q) * 256) + wm * 128 + i * 16 + ml) * 8];
#pragma unroll
      for (int j = 0; j < 4; ++j)
        bfr[j] = *(const bf16x8*)&Bs[cur][(((ks * 4 + q) * 256) + wn * 64 + j * 16 + ml) * 8];
#pragma unroll
      for (int i = 0; i < 8; ++i)
#pragma unroll
        for (int j = 0; j < 4; ++j)
          acc[i][j] = __builtin_amdgcn_mfma_f32_16x16x32_bf16(af[i], bfr[j], acc[i][j], 0, 0, 0);
    }
    __builtin_amdgcn_sched_barrier(0);
    __builtin_amdgcn_s_barrier();
    cur ^= 1;
  }

#pragma unroll
  for (int j = 0; j < 4; ++j) {
    int col = n0 + wn * 64 + j * 16 + ml;
    float bias = out_b[col];
#pragma unroll
    for (int i = 0; i < 8; ++i) {
      int trow = m0 + wm * 128 + i * 16 + q * 4;
#pragma unroll
      for (int v = 0; v < 4; ++v) {
        int t = trow + v;
        out[((size_t)(t & 3) * NN + (t >> 2)) * DD + col] = acc[i][j][v] + bias;
      }
    }
  }
}

extern "C" void kernel_launch(void* const* d_in, const int* in_sizes, int n_in,
                              void* d_out, int out_size, void* d_ws, size_t ws_size,
                              hipStream_t stream) {
  const float* x         = (const float*)d_in[0];
  const float* theta_log = (const float*)d_in[1];
  const float* gamma_log = (const float*)d_in[2];
  const float* nu_w      = (const float*)d_in[3];
  const float* nu_b      = (const float*)d_in[4];
  const float* in_w      = (const float*)d_in[5];
  const float* in_b      = (const float*)d_in[6];
  const float* out_w     = (const float*)d_in[7];
  const float* out_b     = (const float*)d_in[8];
  float* out = (float*)d_out;

  // Workspace layout: 148,897,792 B total (round 0 proved ws_size >= 216 MB)
  char* base = (char*)d_ws;
  unsigned short* U16 = (unsigned short*)base;                 //  67,108,864
  _Float16*       NU  = (_Float16*)(base + 67108864);          //  33,554,432
  unsigned short* Abf = (unsigned short*)(base + 100663296);   //  33,554,432
  unsigned short* W1  = (unsigned short*)(base + 134217728);   //   6,291,456
  unsigned short* W2  = (unsigned short*)(base + 140509184);   //   4,194,304
  float*          chunkA = (float*)(base + 144703488);         //   4,194,304

  conv_x_kernel<<<(BB * NN * DD) / 256, 256, 0, stream>>>(x, Abf);
  conv_w1_kernel<<<(3072 * 1024) / 256, 256, 0, stream>>>(in_w, nu_w, W1);
  conv_w2_kernel<<<(1024 * 1024) / 256, 256, 0, stream>>>(out_w, W2);
  gemm1_mfma<<<dim3(3072 / 256, TT / 256), 512, 0, stream>>>(
      Abf, W1, in_b, nu_b, gamma_log, U16, NU);
  scan_p1_kernel<<<(NC * BB * DD) / 256, 256, 0, stream>>>(U16, NU, theta_log, chunkA);
  scan_p2_kernel<<<(BB * DD) / 256, 256, 0, stream>>>(chunkA);
  scan_p3_kernel<<<NC * BB, 256, 0, stream>>>(U16, NU, theta_log, chunkA);
  gemm2_mfma<<<dim3(1024 / 256, TT / 256), 512, 0, stream>>>(U16, W2, out_b, out);
}